// Round 1
// baseline (1321.400 us; speedup 1.0000x reference)
//
#include <hip/hip_runtime.h>
#include <hip/hip_bf16.h>

// HeteroEmbedding: out[n] = tables[types[n], x[n]]  (pad: x==0 -> 0)
// N = 2,000,000 rows, EMBED = 128 f32, VOCAB = 50,000, NUM_TYPES = 8.
// Pure gather, memory-bound. 32 threads/row, one float4 per thread:
//  - writes: fully coalesced, 1.024 GB
//  - reads : 512 B contiguous burst per row at random table offset
// Table is 204.8 MB < 256 MiB L3, so steady-state reads are L3-resident.

constexpr int kEmbed  = 128;
constexpr int kChunks = kEmbed / 4;   // 32 float4 per row
constexpr int kVocab  = 50000;

__global__ __launch_bounds__(256) void hetero_embed_kernel(
    const int* __restrict__ x,
    const int* __restrict__ types,
    const float4* __restrict__ tables,
    float4* __restrict__ out,
    int n) {
  int tid = blockIdx.x * blockDim.x + threadIdx.x;
  int row = tid >> 5;      // 32 threads per row
  int chunk = tid & 31;    // which float4 within the 128-float row
  if (row >= n) return;

  int idx = x[row];
  int ty  = types[row];

  float4 v;
  if (idx == 0) {
    v = make_float4(0.f, 0.f, 0.f, 0.f);   // padding_idx semantics
  } else {
    size_t src = ((size_t)ty * kVocab + (size_t)idx) * kChunks + chunk;
    v = tables[src];
  }
  out[(size_t)row * kChunks + chunk] = v;
}

extern "C" void kernel_launch(void* const* d_in, const int* in_sizes, int n_in,
                              void* d_out, int out_size, void* d_ws, size_t ws_size,
                              hipStream_t stream) {
  const int* x        = (const int*)d_in[0];
  const int* types    = (const int*)d_in[1];
  const float4* tabs  = (const float4*)d_in[2];
  float4* out         = (float4*)d_out;
  int n = in_sizes[0];

  // 32 threads per row, 256 threads per block -> 8 rows per block
  int blocks = (n + 7) / 8;
  hetero_embed_kernel<<<blocks, 256, 0, stream>>>(x, types, tabs, out, n);
}